// Round 16
// baseline (360.068 us; speedup 1.0000x reference)
//
#include <hip/hip_runtime.h>
#include <hip/hip_bf16.h>
#include <math.h>

#define C_FEAT 384
#define N_VIS (C_FEAT * 9)       // 3456
#define HID 300
#define BN_EPS 1e-5f
#define BATCH 8
#define NROI 1024
#define K2 10
#define NTOT (N_VIS + HID + 4)   // 3760
#define KPAD_DEC 3776
#define KPAD_ENC2 320

typedef _Float16 f16;
typedef f16 f16x8 __attribute__((ext_vector_type(8)));
typedef f16 f16x4 __attribute__((ext_vector_type(4)));
typedef f16 f16x2 __attribute__((ext_vector_type(2)));
typedef float f32x4 __attribute__((ext_vector_type(4)));
typedef int i32x4 __attribute__((ext_vector_type(4)));

// ====================== convert fp32 -> fp16 (hi only) ======================
__global__ void convert_rowmajor(const float* __restrict__ in, f16* __restrict__ oh,
                                 int R, int C, int Cpad)
{
    int idx = blockIdx.x * blockDim.x + threadIdx.x;
    if (idx >= R * Cpad) return;
    int r = idx / Cpad, c = idx % Cpad;
    float v = (c < C) ? in[(size_t)r * C + c] : 0.f;
    oh[idx] = (f16)v;
}

// ====================== transpose + split (hi,lo), f16x8 stores ======================
__global__ void transpose_split(const float* __restrict__ W, int K, int Ntot, int nc0, int NC,
                                int Kpad, f16* __restrict__ Bh, f16* __restrict__ Bl)
{
    __shared__ float T[32][33];
    int k0 = blockIdx.x * 32, n0 = blockIdx.y * 32;
    int tc = threadIdx.x & 31, tr = threadIdx.x >> 5;
    #pragma unroll
    for (int i = 0; i < 4; ++i) {
        int r = tr + i * 8;
        int gk = k0 + r, nloc = n0 + tc, gn = nc0 + nloc;
        float v = 0.f;
        if (gk < K && nloc < NC && gn < Ntot) v = W[(size_t)gk * Ntot + gn];
        T[r][tc] = v;
    }
    __syncthreads();
    int t = threadIdx.x;
    if (t < 128) {
        int nr = t >> 2, kc = (t & 3) * 8;
        int n = n0 + nr;
        if (n < NC) {
            f16x8 hh, ll;
            #pragma unroll
            for (int j = 0; j < 8; ++j) {
                float v = T[kc + j][nr];
                f16 h = (f16)v;
                hh[j] = h;
                ll[j] = (f16)(v - (float)h);
            }
            size_t o = (size_t)n * Kpad + k0 + kc;
            *(f16x8*)&Bh[o] = hh;
            *(f16x8*)&Bl[o] = ll;
        }
    }
}

// ====================== transpose + convert (hi only), f16x8 stores ======================
__global__ void transpose_convert(const float* __restrict__ W, int K, int Ntot, int nc0, int NC,
                                  int Kpad, f16* __restrict__ Bh)
{
    __shared__ float T[32][33];
    int k0 = blockIdx.x * 32, n0 = blockIdx.y * 32;
    int tc = threadIdx.x & 31, tr = threadIdx.x >> 5;
    #pragma unroll
    for (int i = 0; i < 4; ++i) {
        int r = tr + i * 8;
        int gk = k0 + r, nloc = n0 + tc, gn = nc0 + nloc;
        float v = 0.f;
        if (gk < K && nloc < NC && gn < Ntot) v = W[(size_t)gk * Ntot + gn];
        T[r][tc] = v;
    }
    __syncthreads();
    int t = threadIdx.x;
    if (t < 128) {
        int nr = t >> 2, kc = (t & 3) * 8;
        int n = n0 + nr;
        if (n < NC) {
            f16x8 hh;
            #pragma unroll
            for (int j = 0; j < 8; ++j) hh[j] = (f16)T[kc + j][nr];
            *(f16x8*)&Bh[(size_t)n * Kpad + k0 + kc] = hh;
        }
    }
}

// ====================== im2col (single fp16) ======================
__global__ void im2col1_f16(const float* __restrict__ img, f16* __restrict__ ch, int b0, int nb)
{
    int idx = blockIdx.x * blockDim.x + threadIdx.x;
    int total = nb * 3025 * 384;
    if (idx >= total) return;
    int k = idx % 384, r = idx / 384;
    int ow = r % 55, t = r / 55;
    int oh = t % 55, bi = t / 55;
    float v = 0.f;
    if (k < 363) {
        int ic = k / 121, q = k % 121;
        int kh = q / 11, kw = q % 11;
        int ih = oh * 4 - 2 + kh, iw = ow * 4 - 2 + kw;
        if (ih >= 0 && ih < 224 && iw >= 0 && iw < 224)
            v = img[(((size_t)(b0 + bi) * 3 + ic) * 224 + ih) * 224 + iw];
    }
    ch[idx] = (f16)v;
}

__global__ void im2col2_f16(const float* __restrict__ in, f16* __restrict__ ch, int b0, int nb)
{
    int idx = blockIdx.x * blockDim.x + threadIdx.x;
    int total = nb * 729 * 1600;
    if (idx >= total) return;
    int k = idx % 1600, r = idx / 1600;
    int ow = r % 27, t = r / 27;
    int oh = t % 27, bi = t / 27;
    int ic = k / 25, q = k % 25;
    int kh = q / 5, kw = q % 5;
    int ih = oh - 2 + kh, iw = ow - 2 + kw;
    float v = 0.f;
    if (ih >= 0 && ih < 27 && iw >= 0 && iw < 27)
        v = in[(((size_t)(b0 + bi) * 27 + ih) * 27 + iw) * 64 + ic];
    ch[idx] = (f16)v;
}

__global__ void im2col3_f16(const float* __restrict__ in, f16* __restrict__ ch)
{
    int idx = blockIdx.x * blockDim.x + threadIdx.x;
    int total = 8 * 169 * 1728;
    if (idx >= total) return;
    int k = idx % 1728, r = idx / 1728;
    int ow = r % 13, t = r / 13;
    int oh = t % 13, bi = t / 13;
    int ic = k / 9, q = k % 9;
    int kh = q / 3, kw = q % 3;
    int ih = oh - 1 + kh, iw = ow - 1 + kw;
    float v = 0.f;
    if (ih >= 0 && ih < 13 && iw >= 0 && iw < 13)
        v = in[(((size_t)bi * 13 + ih) * 13 + iw) * 192 + ic];
    ch[idx] = (f16)v;
}

// ====================== f16 MFMA GEMM (depth-1 prefetch) ======================
// C(MxN) = A(MxK) @ Bt(NxK)^T. MODE 0:+bias 1:bias+BN+relu 2:bias+relu
// SWZ 0: 2D grid. SWZ 2: 240-block 8m x 30n swizzle. SWZ 3: 480-block 16m x 30n swizzle.
// SPLITK>1: blockIdx.z slices K; raw partials; MODE ignored. PASSES: 1 or 3 (f16x3).
#define LDH 40
template<int TM, int TN, int BS, int MODE, int SWZ, int SPLITK, int PASSES>
__global__ __launch_bounds__(BS) void gemm_f16x3(
    const f16* __restrict__ Ah, const f16* __restrict__ Al, int lda,
    const f16* __restrict__ Bh, const f16* __restrict__ Bl, int ldb,
    float* __restrict__ C, int ldc, int M, int N, int K,
    const float* __restrict__ bias, const float* __restrict__ g,
    const float* __restrict__ be, const float* __restrict__ mean,
    const float* __restrict__ var)
{
    constexpr int NW = BS / 64;
    constexpr int WROWS = NW / 2;
    constexpr int WM = TM / (16 * WROWS);
    constexpr int WN = TN / 32;
    constexpr int AV = TM * 4 / BS;
    constexpr int BV = TN * 4 / BS;
    constexpr bool P3 = (PASSES == 3);
    __shared__ f16 sAh[TM * LDH], sBh[TN * LDH];
    __shared__ f16 sAl[(P3 ? TM : 1) * LDH], sBl[(P3 ? TN : 1) * LDH];
    int tid = threadIdx.x;
    int lane = tid & 63, w = tid >> 6;
    int wr = w >> 1, wc = w & 1;

    int bm, bn;
    if (SWZ == 2) {
        int bid = blockIdx.x;
        int x = bid & 7, l = bid >> 3;           // l in 0..29
        int mt = 2 * (x >> 1) + l / 15;          // 0..7
        int nt = 15 * (x & 1) + l % 15;          // 0..29
        bm = mt * TM; bn = nt * TN;
    } else if (SWZ == 3) {
        int bid = blockIdx.x;
        int x = bid & 7, l = bid >> 3;           // l in 0..59
        int mt = 4 * (x >> 1) + l / 15;          // 0..15
        int nt = 15 * (x & 1) + l % 15;          // 0..29
        bm = mt * TM; bn = nt * TN;
    } else {
        bm = blockIdx.y * TM;
        bn = blockIdx.x * TN;
    }

    int ksBeg = 0, ksEnd = K;
    if (SPLITK > 1) {
        int kc = K / SPLITK;
        ksBeg = blockIdx.z * kc;
        ksEnd = (blockIdx.z == SPLITK - 1) ? K : ksBeg + kc;
    }

    f32x4 acc[WM][WN];
    #pragma unroll
    for (int i = 0; i < WM; ++i)
        #pragma unroll
        for (int j = 0; j < WN; ++j) acc[i][j] = (f32x4){0.f, 0.f, 0.f, 0.f};

    const f16* pAh[AV]; const f16* pAl[AV]; int abase[AV]; bool avld[AV];
    #pragma unroll
    for (int i = 0; i < AV; ++i) {
        int seg = tid * AV + i;
        int row = seg >> 2, ko = (seg & 3) * 8;
        int gr = bm + row;
        avld[i] = gr < M;
        pAh[i] = Ah + (size_t)(avld[i] ? gr : 0) * lda + ko;
        if (P3) pAl[i] = Al + (size_t)(avld[i] ? gr : 0) * lda + ko;
        abase[i] = row * LDH + ko;
    }
    const f16* pBh[BV]; const f16* pBl[BV]; int bbase[BV]; bool bvld[BV];
    #pragma unroll
    for (int i = 0; i < BV; ++i) {
        int seg = tid * BV + i;
        int row = seg >> 2, ko = (seg & 3) * 8;
        int gr = bn + row;
        bvld[i] = gr < N;
        pBh[i] = Bh + (size_t)(bvld[i] ? gr : 0) * ldb + ko;
        if (P3) pBl[i] = Bl + (size_t)(bvld[i] ? gr : 0) * ldb + ko;
        bbase[i] = row * LDH + ko;
    }

    const i32x4 zz = {0, 0, 0, 0};
    i32x4 rAh[AV], rAl[AV], rBh[BV], rBl[BV];

    auto load_step = [&](int k0) {
        #pragma unroll
        for (int i = 0; i < AV; ++i) {
            rAh[i] = avld[i] ? *(const i32x4*)(pAh[i] + k0) : zz;
            if (P3) rAl[i] = avld[i] ? *(const i32x4*)(pAl[i] + k0) : zz;
        }
        #pragma unroll
        for (int i = 0; i < BV; ++i) {
            rBh[i] = bvld[i] ? *(const i32x4*)(pBh[i] + k0) : zz;
            if (P3) rBl[i] = bvld[i] ? *(const i32x4*)(pBl[i] + k0) : zz;
        }
    };
    load_step(ksBeg);

    int kfo = (lane >> 4) * 8;
    int rr = lane & 15;

    for (int k0 = ksBeg; k0 < ksEnd; k0 += 32) {
        __syncthreads();
        #pragma unroll
        for (int i = 0; i < AV; ++i) {
            *(i32x4*)&sAh[abase[i]] = rAh[i];
            if (P3) *(i32x4*)&sAl[abase[i]] = rAl[i];
        }
        #pragma unroll
        for (int i = 0; i < BV; ++i) {
            *(i32x4*)&sBh[bbase[i]] = rBh[i];
            if (P3) *(i32x4*)&sBl[bbase[i]] = rBl[i];
        }
        __syncthreads();
        if (k0 + 32 < ksEnd) load_step(k0 + 32);

        f16x8 fah[WM], fal[WM], fbh[WN], fbl[WN];
        #pragma unroll
        for (int m = 0; m < WM; ++m) {
            int row = wr * (WM * 16) + m * 16 + rr;
            fah[m] = *(const f16x8*)&sAh[row * LDH + kfo];
            if (P3) fal[m] = *(const f16x8*)&sAl[row * LDH + kfo];
        }
        #pragma unroll
        for (int n = 0; n < WN; ++n) {
            int row = wc * (WN * 16) + n * 16 + rr;
            fbh[n] = *(const f16x8*)&sBh[row * LDH + kfo];
            if (P3) fbl[n] = *(const f16x8*)&sBl[row * LDH + kfo];
        }
        #pragma unroll
        for (int m = 0; m < WM; ++m)
            #pragma unroll
            for (int n = 0; n < WN; ++n) {
                acc[m][n] = __builtin_amdgcn_mfma_f32_16x16x32_f16(fah[m], fbh[n], acc[m][n], 0, 0, 0);
                if (P3) {
                    acc[m][n] = __builtin_amdgcn_mfma_f32_16x16x32_f16(fah[m], fbl[n], acc[m][n], 0, 0, 0);
                    acc[m][n] = __builtin_amdgcn_mfma_f32_16x16x32_f16(fal[m], fbh[n], acc[m][n], 0, 0, 0);
                }
            }
    }

    int crl = lane >> 4;
    size_t zoff = (SPLITK > 1) ? (size_t)blockIdx.z * M : 0;
    #pragma unroll
    for (int m = 0; m < WM; ++m) {
        #pragma unroll
        for (int n = 0; n < WN; ++n) {
            int gn = bn + wc * (WN * 16) + n * 16 + rr;
            if (gn >= N) continue;
            #pragma unroll
            for (int r = 0; r < 4; ++r) {
                int gm = bm + wr * (WM * 16) + m * 16 + crl * 4 + r;
                if (gm >= M) continue;
                if (SPLITK > 1) {
                    C[(zoff + gm) * ldc + gn] = acc[m][n][r];
                } else {
                    float v = acc[m][n][r] + bias[gn];
                    if (MODE == 1) {
                        float s = g[gn] / sqrtf(var[gn] + BN_EPS);
                        v = (v - mean[gn]) * s + be[gn];
                        v = fmaxf(v, 0.f);
                    } else if (MODE == 2) {
                        v = fmaxf(v, 0.f);
                    }
                    C[(size_t)gm * ldc + gn] = v;
                }
            }
        }
    }
}

// ====================== split-K reduce + epilogue (fp32 out) ======================
template<int MODE>
__global__ void reduce_ep(const float* __restrict__ part, float* __restrict__ C,
                          int M, int N, int ldc, int KS,
                          const float* __restrict__ bias, const float* __restrict__ g,
                          const float* __restrict__ be, const float* __restrict__ mean,
                          const float* __restrict__ var)
{
    int idx = blockIdx.x * blockDim.x + threadIdx.x;
    if (idx >= M * N) return;
    int m = idx / N, n = idx % N;
    float v = 0.f;
    for (int ks = 0; ks < KS; ++ks) v += part[((size_t)ks * M + m) * N + n];
    v += bias[n];
    if (MODE == 1) {
        float s = g[n] / sqrtf(var[n] + BN_EPS);
        v = (v - mean[n]) * s + be[n];
        v = fmaxf(v, 0.f);
    } else if (MODE == 2) {
        v = fmaxf(v, 0.f);
    }
    C[(size_t)m * ldc + n] = v;
}

// ====================== split-K reduce + BN/relu -> f16 (k-padded) ======================
__global__ void reduce_ep_f16(const float* __restrict__ part, f16* __restrict__ Ch,
                              int M, int N, int Npad, int KS,
                              const float* __restrict__ bias, const float* __restrict__ g,
                              const float* __restrict__ be, const float* __restrict__ mean,
                              const float* __restrict__ var)
{
    int idx = blockIdx.x * blockDim.x + threadIdx.x;
    if (idx >= M * Npad) return;
    int m = idx / Npad, n = idx % Npad;
    float v = 0.f;
    if (n < N) {
        for (int ks = 0; ks < KS; ++ks) v += part[((size_t)ks * M + m) * N + n];
        v += bias[n];
        float s = g[n] / sqrtf(var[n] + BN_EPS);
        v = (v - mean[n]) * s + be[n];
        v = fmaxf(v, 0.f);
    }
    Ch[(size_t)m * Npad + n] = (f16)v;
}

// ====================== NHWC maxpool ======================
__global__ void maxpool3s2_nhwc(const float* __restrict__ in, float* __restrict__ out,
                                int Bn, int C, int Hin, int Win, int Hout, int Wout)
{
    int idx = blockIdx.x * blockDim.x + threadIdx.x;
    int total = Bn * Hout * Wout * C;
    if (idx >= total) return;
    int c = idx % C, t = idx / C;
    int ow = t % Wout; t /= Wout;
    int oh = t % Hout; int b = t / Hout;
    const float* base = in + (((size_t)b * Hin + oh * 2) * Win + ow * 2) * C + c;
    float v = -INFINITY;
    #pragma unroll
    for (int kh = 0; kh < 3; ++kh)
        #pragma unroll
        for (int kw = 0; kw < 3; ++kw)
            v = fmaxf(v, base[((size_t)kh * Win + kw) * C]);
    out[idx] = v;
}

// ====================== ROI max-pool -> (own_h, own_l) f16 pair; row N zeroed ======================
__global__ void roi_pool_kernel(const float* __restrict__ feat, const float* __restrict__ bboxes,
                                f16* __restrict__ own_h, f16* __restrict__ own_l,
                                int N, int C, int H, int W)
{
    int idx = blockIdx.x * blockDim.x + threadIdx.x;
    if (idx >= (N + 1) * C) return;
    int n = idx / C, c = idx % C;
    f16* oh16 = own_h + (size_t)n * (C * 9) + (size_t)c * 9;
    f16* ol16 = own_l + (size_t)n * (C * 9) + (size_t)c * 9;
    if (n == N) {
        #pragma unroll
        for (int j = 0; j < 9; ++j) { oh16[j] = (f16)0.f; ol16[j] = (f16)0.f; }
        return;
    }
    const float* bb = bboxes + (size_t)n * 5;
    int img = (int)bb[0];
    const float SC = 13.0f / 224.0f;
    int x1 = (int)rintf(bb[1] * SC);
    int y1 = (int)rintf(bb[2] * SC);
    int x2 = (int)rintf(bb[3] * SC);
    int y2 = (int)rintf(bb[4] * SC);
    int roi_w = max(x2 - x1 + 1, 1);
    int roi_h = max(y2 - y1 + 1, 1);
    const float* f = feat + (size_t)img * H * W * C + c;
    for (int ph = 0; ph < 3; ++ph) {
        int hstart = min(max(y1 + (ph * roi_h) / 3, 0), H);
        int hend   = min(max(y1 + ((ph + 1) * roi_h + 2) / 3, 0), H);
        for (int pw = 0; pw < 3; ++pw) {
            int wstart = min(max(x1 + (pw * roi_w) / 3, 0), W);
            int wend   = min(max(x1 + ((pw + 1) * roi_w + 2) / 3, 0), W);
            float v;
            if (hend <= hstart || wend <= wstart) {
                v = 0.f;
            } else {
                v = -INFINITY;
                for (int hh = hstart; hh < hend; ++hh)
                    for (int ww = wstart; ww < wend; ++ww)
                        v = fmaxf(v, f[((size_t)hh * W + ww) * C]);
            }
            f16 h = (f16)v;
            oh16[ph * 3 + pw] = h;
            ol16[ph * 3 + pw] = (f16)(v - (float)h);
        }
    }
}

// ====================== attention projections ======================
__global__ __launch_bounds__(128) void proj_kernel(
    const float* __restrict__ enc_all, const float* __restrict__ att_w,
    float* __restrict__ s_own, float* __restrict__ proj_hi, int R, int H, int Nroi)
{
    int r = blockIdx.x, tid = threadIdx.x;
    const float* row = enc_all + (size_t)r * H;
    float plo = 0.f, phi = 0.f;
    for (int hh = tid; hh < H; hh += 128) {
        float v = row[hh];
        plo += v * att_w[hh];
        phi += v * att_w[H + hh];
    }
    __shared__ float slo[128], shi[128];
    slo[tid] = plo; shi[tid] = phi;
    __syncthreads();
    for (int s = 64; s > 0; s >>= 1) {
        if (tid < s) { slo[tid] += slo[tid + s]; shi[tid] += shi[tid + s]; }
        __syncthreads();
    }
    if (tid == 0) {
        if (r < Nroi) s_own[r] = slo[0];
        proj_hi[r] = shi[0];
    }
}

// ====================== attention softmax + combine -> comb_h/comb_l directly ======================
__global__ __launch_bounds__(512) void att_combine_kernel(
    const float* __restrict__ enc_all, const int* __restrict__ ci,
    const float* __restrict__ s_own, const float* __restrict__ proj_hi,
    const float* __restrict__ att_b,
    const f16* __restrict__ own_h, const f16* __restrict__ own_l,
    const float* __restrict__ bboxes,
    f16* __restrict__ comb_h, f16* __restrict__ comb_l,
    int N, int H)
{
    int n = blockIdx.x, tid = threadIdx.x;
    __shared__ float wts[K2];
    __shared__ int rows[K2];
    if (tid < K2) {
        int idx = ci[(size_t)n * K2 + tid];
        int row = (idx < 0) ? N : idx;
        rows[tid] = row;
        wts[tid] = s_own[n] + proj_hi[row] + att_b[0];
    }
    __syncthreads();
    if (tid == 0) {
        float mx = wts[0];
        #pragma unroll
        for (int k = 1; k < K2; ++k) mx = fmaxf(mx, wts[k]);
        float sum = 0.f;
        float e[K2];
        #pragma unroll
        for (int k = 0; k < K2; ++k) { e[k] = expf(wts[k] - mx); sum += e[k]; }
        float inv = 1.f / sum;
        #pragma unroll
        for (int k = 0; k < K2; ++k) wts[k] = e[k] * inv;
    }
    __syncthreads();

    f16* ch = comb_h + (size_t)n * KPAD_DEC;
    f16* cl = comb_l + (size_t)n * KPAD_DEC;

    if (tid < H) {
        float acc = 0.f;
        #pragma unroll
        for (int k = 0; k < K2; ++k)
            acc += wts[k] * enc_all[(size_t)rows[k] * H + tid];
        f16 h = (f16)acc;
        ch[N_VIS + tid] = h;
        cl[N_VIS + tid] = (f16)(acc - (float)h);
    }
    {
        const f16x8* oh8 = (const f16x8*)(own_h + (size_t)n * N_VIS);
        const f16x8* ol8 = (const f16x8*)(own_l + (size_t)n * N_VIS);
        f16x8* ch8 = (f16x8*)ch;
        f16x8* cl8 = (f16x8*)cl;
        for (int j = tid; j < N_VIS / 8; j += 512) {
            ch8[j] = oh8[j];
            cl8[j] = ol8[j];
        }
    }
    if (tid >= 488 && tid < 504) {
        int col = NTOT + (tid - 488);
        ch[col] = (f16)0.f;
        cl[col] = (f16)0.f;
    }
    if (tid >= 508) {
        int j = tid - 508;
        float x1 = bboxes[(size_t)n * 5 + 1];
        float y1 = bboxes[(size_t)n * 5 + 2];
        float x2 = bboxes[(size_t)n * 5 + 3];
        float y2 = bboxes[(size_t)n * 5 + 4];
        float vals[4] = { x1, y1, x2 - x1, y2 - y1 };
        float v = vals[j];
        f16 h = (f16)v;
        ch[N_VIS + HID + j] = h;
        cl[N_VIS + HID + j] = (f16)(v - (float)h);
    }
}

// ====================== out = h @ w2 + b2 (fallback) ======================
__global__ __launch_bounds__(256) void gemv4_kernel(
    const float* __restrict__ h, const float* __restrict__ w2,
    const float* __restrict__ b2, float* __restrict__ out, int K)
{
    int m = blockIdx.x, tid = threadIdx.x;
    const float* hr = h + (size_t)m * K;
    float a0 = 0.f, a1 = 0.f, a2 = 0.f, a3 = 0.f;
    for (int k = tid; k < K; k += 256) {
        float x = hr[k];
        const float* wr = w2 + (size_t)k * 4;
        a0 += x * wr[0]; a1 += x * wr[1]; a2 += x * wr[2]; a3 += x * wr[3];
    }
    __shared__ float red[256][4];
    red[tid][0] = a0; red[tid][1] = a1; red[tid][2] = a2; red[tid][3] = a3;
    __syncthreads();
    for (int s = 128; s > 0; s >>= 1) {
        if (tid < s) {
            #pragma unroll
            for (int j = 0; j < 4; ++j) red[tid][j] += red[tid + s][j];
        }
        __syncthreads();
    }
    if (tid < 4) out[(size_t)m * 4 + tid] = red[0][tid] + b2[tid];
}

// ====================== fused: (part0+part1) -> BN/relu -> @ w2 + b2 ======================
__global__ __launch_bounds__(256) void gemv4_fused_kernel(
    const float* __restrict__ part, const float* __restrict__ w2,
    const float* __restrict__ b2, const float* __restrict__ bias,
    const float* __restrict__ g, const float* __restrict__ be,
    const float* __restrict__ mean, const float* __restrict__ var,
    float* __restrict__ out, int M, int K)
{
    int m = blockIdx.x, tid = threadIdx.x;
    const float* p0 = part + (size_t)m * K;
    const float* p1 = part + ((size_t)M + m) * K;
    float a0 = 0.f, a1 = 0.f, a2 = 0.f, a3 = 0.f;
    for (int k = tid; k < K; k += 256) {
        float v = p0[k] + p1[k] + bias[k];
        float s = g[k] / sqrtf(var[k] + BN_EPS);
        v = (v - mean[k]) * s + be[k];
        v = fmaxf(v, 0.f);
        const float* wr = w2 + (size_t)k * 4;
        a0 += v * wr[0]; a1 += v * wr[1]; a2 += v * wr[2]; a3 += v * wr[3];
    }
    __shared__ float red[256][4];
    red[tid][0] = a0; red[tid][1] = a1; red[tid][2] = a2; red[tid][3] = a3;
    __syncthreads();
    for (int s = 128; s > 0; s >>= 1) {
        if (tid < s) {
            #pragma unroll
            for (int j = 0; j < 4; ++j) red[tid][j] += red[tid + s][j];
        }
        __syncthreads();
    }
    if (tid < 4) out[(size_t)m * 4 + tid] = red[0][tid] + b2[tid];
}

extern "C" void kernel_launch(void* const* d_in, const int* in_sizes, int n_in,
                              void* d_out, int out_size, void* d_ws, size_t ws_size,
                              hipStream_t stream)
{
    const float* images = (const float*)d_in[0];
    const float* bboxes = (const float*)d_in[1];
    const int*   ci     = (const int*)  d_in[2];
    const float* c1w = (const float*)d_in[3];
    const float* c1b = (const float*)d_in[4];
    const float* c2w = (const float*)d_in[5];
    const float* c2b = (const float*)d_in[6];
    const float* c3w = (const float*)d_in[7];
    const float* c3b = (const float*)d_in[8];
    const float* enc_w1 = (const float*)d_in[9];
    const float* enc_b1 = (const float*)d_in[10];
    const float* enc_g  = (const float*)d_in[11];
    const float* enc_be = (const float*)d_in[12];
    const float* enc_m  = (const float*)d_in[13];
    const float* enc_v  = (const float*)d_in[14];
    const float* enc_w2 = (const float*)d_in[15];
    const float* enc_b2 = (const float*)d_in[16];
    const float* att_w  = (const float*)d_in[17];
    const float* att_b  = (const float*)d_in[18];
    const float* dec_w1 = (const float*)d_in[19];
    const float* dec_b1 = (const float*)d_in[20];
    const float* dec_g  = (const float*)d_in[21];
    const float* dec_be = (const float*)d_in[22];
    const float* dec_m  = (const float*)d_in[23];
    const float* dec_v  = (const float*)d_in[24];
    const float* dec_w2 = (const float*)d_in[25];
    const float* dec_b2 = (const float*)d_in[26];
    float* out = (float*)d_out;

    float* ws = (float*)d_ws;
    size_t off = 0;
    auto alloc = [&](size_t n) { float* p = ws + off; off += (n + 255) & ~(size_t)255; return p; };

    float* own      = alloc((size_t)(NROI + 1) * N_VIS);       // region reused for comb_h/comb_l
    float* featN    = alloc((size_t)BATCH * 13 * 13 * C_FEAT);
    float* mid      = alloc((size_t)(NROI + 1) * HID);         // fallback path only
    float* enc_all  = alloc((size_t)(NROI + 1) * HID);
    float* s_own    = alloc(NROI);
    float* proj_hi  = alloc(NROI + 1);
    float* combined = alloc((size_t)NROI * NTOT);
    float* hbuf     = alloc((size_t)NROI * NTOT);
    size_t base_off = off;

    const size_t BTD_FL = 7128320;
    bool full_dec = (ws_size >= (base_off + 2 * BTD_FL) * sizeof(float));
    float* Btd_h_f = ws + base_off;
    float* Btd_l_f = ws + base_off + BTD_FL;

    float* S = combined;

    f16* wt1_h = (f16*)(S + 6651904);
    f16* wt2_h = wt1_h + 24576;
    f16* wt3_h = wt2_h + 307200;

    convert_rowmajor<<<(64 * 384 + 255) / 256, 256, 0, stream>>>(c1w, wt1_h, 64, 363, 384);
    convert_rowmajor<<<(192 * 1600 + 255) / 256, 256, 0, stream>>>(c2w, wt2_h, 192, 1600, 1600);
    convert_rowmajor<<<(384 * 1728 + 255) / 256, 256, 0, stream>>>(c3w, wt3_h, 384, 1728, 1728);

    float* conv1o = S;
    float* pool1  = S + 1548800;
    float* conv2o = S;

    if (full_dec) {
        f16* colF = (f16*)Btd_h_f;
        float* part2 = S + 1922048;
        float* pool2 = S + 4161536;
        float* part3 = S;

        {
            int total = 8 * 3025 * 384;
            im2col1_f16<<<(total + 255) / 256, 256, 0, stream>>>(images, colF, 0, 8);
            dim3 grid(1, (8 * 3025 + 63) / 64);
            gemm_f16x3<64, 64, 256, 2, 0, 1, 1><<<grid, 256, 0, stream>>>(
                colF, nullptr, 384, wt1_h, nullptr, 384,
                conv1o, 64, 8 * 3025, 64, 384,
                c1b, nullptr, nullptr, nullptr, nullptr);
        }
        maxpool3s2_nhwc<<<(BATCH * 27 * 27 * 64 + 255) / 256, 256, 0, stream>>>(
            conv1o, pool1, BATCH, 64, 55, 55, 27, 27);

        {
            int total = 8 * 729 * 1600;
            im2col2_f16<<<(total + 255) / 256, 256, 0, stream>>>(pool1, colF, 0, 8);
            dim3 grid(3, (8 * 729 + 63) / 64, 2);
            gemm_f16x3<64, 64, 256, 0, 0, 2, 1><<<grid, 256, 0, stream>>>(
                colF, nullptr, 1600, wt2_h, nullptr, 1600,
                part2, 192, 8 * 729, 192, 1600,
                nullptr, nullptr, nullptr, nullptr, nullptr);
            reduce_ep<2><<<(8 * 729 * 192 + 255) / 256, 256, 0, stream>>>(
                part2, conv2o, 8 * 729, 192, 192, 2, c2b, nullptr, nullptr, nullptr, nullptr);
        }
        maxpool3s2_nhwc<<<(BATCH * 13 * 13 * 192 + 255) / 256, 256, 0, stream>>>(
            conv2o, pool2, BATCH, 192, 27, 27, 13, 13);

        {
            int total = 8 * 169 * 1728;
            im2col3_f16<<<(total + 255) / 256, 256, 0, stream>>>(pool2, colF);
            dim3 grid(6, (8 * 169 + 63) / 64, 2);
            gemm_f16x3<64, 64, 256, 0, 0, 2, 1><<<grid, 256, 0, stream>>>(
                colF, nullptr, 1728, wt3_h, nullptr, 1728,
                part3, 384, 8 * 169, 384, 1728,
                nullptr, nullptr, nullptr, nullptr, nullptr);
            reduce_ep<0><<<(8 * 169 * 384 + 255) / 256, 256, 0, stream>>>(
                part3, featN, 8 * 169, 384, 384, 2, c3b, nullptr, nullptr, nullptr, nullptr);
        }
    } else {
        f16* col_h = (f16*)(S + 1922048);
        float* pool2 = S + 1548800;
        for (int ch = 0; ch < 2; ++ch) {
            int b0 = ch * 4, nb = 4;
            int total = nb * 3025 * 384;
            im2col1_f16<<<(total + 255) / 256, 256, 0, stream>>>(images, col_h, b0, nb);
            dim3 grid(1, (nb * 3025 + 63) / 64);
            gemm_f16x3<64, 64, 256, 2, 0, 1, 1><<<grid, 256, 0, stream>>>(
                col_h, nullptr, 384, wt1_h, nullptr, 384,
                conv1o + (size_t)b0 * 3025 * 64, 64, nb * 3025, 64, 384,
                c1b, nullptr, nullptr, nullptr, nullptr);
        }
        maxpool3s2_nhwc<<<(BATCH * 27 * 27 * 64 + 255) / 256, 256, 0, stream>>>(
            conv1o, pool1, BATCH, 64, 55, 55, 27, 27);
        for (int ch = 0; ch < 2; ++ch) {
            int b0 = ch * 4, nb = 4;
            int total = nb * 729 * 1600;
            im2col2_f16<<<(total + 255) / 256, 256, 0, stream>>>(pool1, col_h, b0, nb);
            dim3 grid(3, (nb * 729 + 63) / 64);
            gemm_f16x3<64, 64, 256, 2, 0, 1, 1><<<grid, 256, 0, stream>>>(
                col_h, nullptr, 1600, wt2_h, nullptr, 1600,
                conv2o + (size_t)b0 * 729 * 192, 192, nb * 729, 192, 1600,
                c2b, nullptr, nullptr, nullptr, nullptr);
        }
        maxpool3s2_nhwc<<<(BATCH * 13 * 13 * 192 + 255) / 256, 256, 0, stream>>>(
            conv2o, pool2, BATCH, 192, 27, 27, 13, 13);
        {
            int total = 8 * 169 * 1728;
            im2col3_f16<<<(total + 255) / 256, 256, 0, stream>>>(pool2, col_h);
            dim3 grid(6, (8 * 169 + 63) / 64);
            gemm_f16x3<64, 64, 256, 0, 0, 1, 1><<<grid, 256, 0, stream>>>(
                col_h, nullptr, 1728, wt3_h, nullptr, 1728,
                featN, 384, 8 * 169, 384, 1728,
                c3b, nullptr, nullptr, nullptr, nullptr);
        }
    }

    // ---- ROI pool -> own_h + own_l (f16), zero row fused ----
    f16* own_h = (f16*)(S + 0);
    f16* own_l = (f16*)(S + 1771200);
    roi_pool_kernel<<<((NROI + 1) * C_FEAT + 255) / 256, 256, 0, stream>>>(
        featN, bboxes, own_h, own_l, NROI, C_FEAT, 13, 13);

    // ---- encoder layer 1 (1-pass fp16) ----
    f16* encB_h = (f16*)(S + 3542400);
    {
        dim3 tg((N_VIS + 31) / 32, (HID + 31) / 32);
        transpose_convert<<<tg, 256, 0, stream>>>(enc_w1, N_VIS, HID, 0, HID, N_VIS, encB_h);
    }
    f16* mid_h = (f16*)(S + 5290800);
    f16* e2B_h = (f16*)(S + 5454800);
    if (full_dec) {
        float* part1 = S + 4060800;
        dim3 grid((HID + 63) / 64, (NROI + 1 + 63) / 64, 4);
        gemm_f16x3<64, 64, 256, 0, 0, 4, 1><<<grid, 256, 0, stream>>>(
            own_h, nullptr, N_VIS, encB_h, nullptr, N_VIS,
            part1, HID, NROI + 1, HID, N_VIS,
            nullptr, nullptr, nullptr, nullptr, nullptr);
        reduce_ep_f16<<<((NROI + 1) * KPAD_ENC2 + 255) / 256, 256, 0, stream>>>(
            part1, mid_h, NROI + 1, HID, KPAD_ENC2, 4, enc_b1, enc_g, enc_be, enc_m, enc_v);
    } else {
        dim3 grid((HID + 63) / 64, (NROI + 1 + 63) / 64);
        gemm_f16x3<64, 64, 256, 1, 0, 1, 1><<<grid, 256, 0, stream>>>(
            own_h, nullptr, N_VIS, encB_h, nullptr, N_VIS,
            mid, HID, NROI + 1, HID, N_VIS,
            enc_b1, enc_g, enc_be, enc_m, enc_v);
        convert_rowmajor<<<((NROI + 1) * KPAD_ENC2 + 255) / 256, 256, 0, stream>>>(
            mid, mid_h, NROI + 1, HID, KPAD_ENC2);
    }

    // ---- encoder layer 2 (1-pass fp16) ----
    {
        dim3 tg((HID + 31) / 32, (HID + 31) / 32);
        transpose_convert<<<tg, 256, 0, stream>>>(enc_w2, HID, HID, 0, HID, KPAD_ENC2, e2B_h);
    }
    {
        dim3 grid((HID + 63) / 64, (NROI + 1 + 63) / 64);
        gemm_f16x3<64, 64, 256, 0, 0, 1, 1><<<grid, 256, 0, stream>>>(
            mid_h, nullptr, KPAD_ENC2, e2B_h, nullptr, KPAD_ENC2,
            enc_all, HID, NROI + 1, HID, KPAD_ENC2,
            enc_b2, nullptr, nullptr, nullptr, nullptr);
    }

    // ---- attention -> comb_h/comb_l directly ----
    f16* comb_h = (f16*)own;
    f16* comb_l = (f16*)(own + 1933312);
    proj_kernel<<<NROI + 1, 128, 0, stream>>>(enc_all, att_w, s_own, proj_hi, NROI + 1, HID, NROI);
    att_combine_kernel<<<NROI, 512, 0, stream>>>(enc_all, ci, s_own, proj_hi, att_b,
                                                 own_h, own_l, bboxes, comb_h, comb_l,
                                                 NROI, HID);

    // ---- decoder layer 1: 64x128 tiles, 256 thr, split-K 2 -> 960 blocks (~30 waves/CU) ----
    if (full_dec) {
        f16* Btd_h = (f16*)Btd_h_f;
        f16* Btd_l = (f16*)Btd_l_f;
        dim3 tg(KPAD_DEC / 32, KPAD_DEC / 32);
        transpose_split<<<tg, 256, 0, stream>>>(dec_w1, NTOT, NTOT, 0, KPAD_DEC, KPAD_DEC, Btd_h, Btd_l);
        float* part = combined;                // spans combined+hbuf (2 slices)
        dim3 grid(480, 1, 2);
        gemm_f16x3<64, 128, 256, 1, 3, 2, 3><<<grid, 256, 0, stream>>>(
            comb_h, comb_l, KPAD_DEC, Btd_h, Btd_l, KPAD_DEC,
            part, NTOT, NROI, NTOT, KPAD_DEC,
            nullptr, nullptr, nullptr, nullptr, nullptr);
        gemv4_fused_kernel<<<NROI, 256, 0, stream>>>(
            part, dec_w2, dec_b2, dec_b1, dec_g, dec_be, dec_m, dec_v,
            out, NROI, NTOT);
    } else {
        f16* Btc_h = (f16*)(S + 0);
        f16* Btc_l = (f16*)(S + 1774720);
        for (int c = 0; c < 4; ++c) {
            int nc0 = c * 940, NC = 940;
            dim3 tg(KPAD_DEC / 32, (NC + 31) / 32);
            transpose_split<<<tg, 256, 0, stream>>>(dec_w1, NTOT, NTOT, nc0, NC, KPAD_DEC, Btc_h, Btc_l);
            dim3 grid((NC + 63) / 64, NROI / 64);
            gemm_f16x3<64, 64, 256, 1, 0, 1, 3><<<grid, 256, 0, stream>>>(
                comb_h, comb_l, KPAD_DEC, Btc_h, Btc_l, KPAD_DEC,
                hbuf + nc0, NTOT, NROI, NC, KPAD_DEC,
                dec_b1 + nc0, dec_g + nc0, dec_be + nc0, dec_m + nc0, dec_v + nc0);
        }
        gemv4_kernel<<<NROI, 256, 0, stream>>>(hbuf, dec_w2, dec_b2, out, NTOT);
    }
}

// Round 17
// 302.935 us; speedup vs baseline: 1.1886x; 1.1886x over previous
//
#include <hip/hip_runtime.h>
#include <hip/hip_bf16.h>
#include <math.h>

#define C_FEAT 384
#define N_VIS (C_FEAT * 9)       // 3456
#define HID 300
#define BN_EPS 1e-5f
#define BATCH 8
#define NROI 1024
#define K2 10
#define NTOT (N_VIS + HID + 4)   // 3760
#define KPAD_DEC 3776
#define KPAD_ENC2 320

typedef _Float16 f16;
typedef f16 f16x8 __attribute__((ext_vector_type(8)));
typedef f16 f16x4 __attribute__((ext_vector_type(4)));
typedef f16 f16x2 __attribute__((ext_vector_type(2)));
typedef float f32x4 __attribute__((ext_vector_type(4)));
typedef int i32x4 __attribute__((ext_vector_type(4)));

// ====================== convert fp32 -> fp16 (hi only) ======================
__global__ void convert_rowmajor(const float* __restrict__ in, f16* __restrict__ oh,
                                 int R, int C, int Cpad)
{
    int idx = blockIdx.x * blockDim.x + threadIdx.x;
    if (idx >= R * Cpad) return;
    int r = idx / Cpad, c = idx % Cpad;
    float v = (c < C) ? in[(size_t)r * C + c] : 0.f;
    oh[idx] = (f16)v;
}

// ====================== transpose + split (hi,lo), f16x8 stores ======================
__global__ void transpose_split(const float* __restrict__ W, int K, int Ntot, int nc0, int NC,
                                int Kpad, f16* __restrict__ Bh, f16* __restrict__ Bl)
{
    __shared__ float T[32][33];
    int k0 = blockIdx.x * 32, n0 = blockIdx.y * 32;
    int tc = threadIdx.x & 31, tr = threadIdx.x >> 5;
    #pragma unroll
    for (int i = 0; i < 4; ++i) {
        int r = tr + i * 8;
        int gk = k0 + r, nloc = n0 + tc, gn = nc0 + nloc;
        float v = 0.f;
        if (gk < K && nloc < NC && gn < Ntot) v = W[(size_t)gk * Ntot + gn];
        T[r][tc] = v;
    }
    __syncthreads();
    int t = threadIdx.x;
    if (t < 128) {
        int nr = t >> 2, kc = (t & 3) * 8;
        int n = n0 + nr;
        if (n < NC) {
            f16x8 hh, ll;
            #pragma unroll
            for (int j = 0; j < 8; ++j) {
                float v = T[kc + j][nr];
                f16 h = (f16)v;
                hh[j] = h;
                ll[j] = (f16)(v - (float)h);
            }
            size_t o = (size_t)n * Kpad + k0 + kc;
            *(f16x8*)&Bh[o] = hh;
            *(f16x8*)&Bl[o] = ll;
        }
    }
}

// ====================== transpose + convert (hi only), f16x8 stores ======================
__global__ void transpose_convert(const float* __restrict__ W, int K, int Ntot, int nc0, int NC,
                                  int Kpad, f16* __restrict__ Bh)
{
    __shared__ float T[32][33];
    int k0 = blockIdx.x * 32, n0 = blockIdx.y * 32;
    int tc = threadIdx.x & 31, tr = threadIdx.x >> 5;
    #pragma unroll
    for (int i = 0; i < 4; ++i) {
        int r = tr + i * 8;
        int gk = k0 + r, nloc = n0 + tc, gn = nc0 + nloc;
        float v = 0.f;
        if (gk < K && nloc < NC && gn < Ntot) v = W[(size_t)gk * Ntot + gn];
        T[r][tc] = v;
    }
    __syncthreads();
    int t = threadIdx.x;
    if (t < 128) {
        int nr = t >> 2, kc = (t & 3) * 8;
        int n = n0 + nr;
        if (n < NC) {
            f16x8 hh;
            #pragma unroll
            for (int j = 0; j < 8; ++j) hh[j] = (f16)T[kc + j][nr];
            *(f16x8*)&Bh[(size_t)n * Kpad + k0 + kc] = hh;
        }
    }
}

// ====================== im2col (single fp16) ======================
__global__ void im2col1_f16(const float* __restrict__ img, f16* __restrict__ ch, int b0, int nb)
{
    int idx = blockIdx.x * blockDim.x + threadIdx.x;
    int total = nb * 3025 * 384;
    if (idx >= total) return;
    int k = idx % 384, r = idx / 384;
    int ow = r % 55, t = r / 55;
    int oh = t % 55, bi = t / 55;
    float v = 0.f;
    if (k < 363) {
        int ic = k / 121, q = k % 121;
        int kh = q / 11, kw = q % 11;
        int ih = oh * 4 - 2 + kh, iw = ow * 4 - 2 + kw;
        if (ih >= 0 && ih < 224 && iw >= 0 && iw < 224)
            v = img[(((size_t)(b0 + bi) * 3 + ic) * 224 + ih) * 224 + iw];
    }
    ch[idx] = (f16)v;
}

__global__ void im2col2_f16(const float* __restrict__ in, f16* __restrict__ ch, int b0, int nb)
{
    int idx = blockIdx.x * blockDim.x + threadIdx.x;
    int total = nb * 729 * 1600;
    if (idx >= total) return;
    int k = idx % 1600, r = idx / 1600;
    int ow = r % 27, t = r / 27;
    int oh = t % 27, bi = t / 27;
    int ic = k / 25, q = k % 25;
    int kh = q / 5, kw = q % 5;
    int ih = oh - 2 + kh, iw = ow - 2 + kw;
    float v = 0.f;
    if (ih >= 0 && ih < 27 && iw >= 0 && iw < 27)
        v = in[(((size_t)(b0 + bi) * 27 + ih) * 27 + iw) * 64 + ic];
    ch[idx] = (f16)v;
}

__global__ void im2col3_f16(const float* __restrict__ in, f16* __restrict__ ch)
{
    int idx = blockIdx.x * blockDim.x + threadIdx.x;
    int total = 8 * 169 * 1728;
    if (idx >= total) return;
    int k = idx % 1728, r = idx / 1728;
    int ow = r % 13, t = r / 13;
    int oh = t % 13, bi = t / 13;
    int ic = k / 9, q = k % 9;
    int kh = q / 3, kw = q % 3;
    int ih = oh - 1 + kh, iw = ow - 1 + kw;
    float v = 0.f;
    if (ih >= 0 && ih < 13 && iw >= 0 && iw < 13)
        v = in[(((size_t)bi * 13 + ih) * 13 + iw) * 192 + ic];
    ch[idx] = (f16)v;
}

// ====================== f16 MFMA GEMM (depth-1 prefetch — proven config) ======================
// C(MxN) = A(MxK) @ Bt(NxK)^T. MODE 0:+bias 1:bias+BN+relu 2:bias+relu
// SWZ 0: 2D grid. SWZ 2: 240-block 8m x 30n XCD-rectangular swizzle.
// SPLITK>1: blockIdx.z slices K; raw partials; MODE ignored. PASSES: 1 or 3 (f16x3).
#define LDH 40
template<int TM, int TN, int BS, int MODE, int SWZ, int SPLITK, int PASSES>
__global__ __launch_bounds__(BS) void gemm_f16x3(
    const f16* __restrict__ Ah, const f16* __restrict__ Al, int lda,
    const f16* __restrict__ Bh, const f16* __restrict__ Bl, int ldb,
    float* __restrict__ C, int ldc, int M, int N, int K,
    const float* __restrict__ bias, const float* __restrict__ g,
    const float* __restrict__ be, const float* __restrict__ mean,
    const float* __restrict__ var)
{
    constexpr int NW = BS / 64;
    constexpr int WROWS = NW / 2;
    constexpr int WM = TM / (16 * WROWS);
    constexpr int WN = TN / 32;
    constexpr int AV = TM * 4 / BS;
    constexpr int BV = TN * 4 / BS;
    constexpr bool P3 = (PASSES == 3);
    __shared__ f16 sAh[TM * LDH], sBh[TN * LDH];
    __shared__ f16 sAl[(P3 ? TM : 1) * LDH], sBl[(P3 ? TN : 1) * LDH];
    int tid = threadIdx.x;
    int lane = tid & 63, w = tid >> 6;
    int wr = w >> 1, wc = w & 1;

    int bm, bn;
    if (SWZ == 2) {
        int bid = blockIdx.x;
        int x = bid & 7, l = bid >> 3;           // l in 0..29
        int mt = 2 * (x >> 1) + l / 15;          // 0..7
        int nt = 15 * (x & 1) + l % 15;          // 0..29
        bm = mt * TM; bn = nt * TN;
    } else {
        bm = blockIdx.y * TM;
        bn = blockIdx.x * TN;
    }

    int ksBeg = 0, ksEnd = K;
    if (SPLITK > 1) {
        int kc = K / SPLITK;
        ksBeg = blockIdx.z * kc;
        ksEnd = (blockIdx.z == SPLITK - 1) ? K : ksBeg + kc;
    }

    f32x4 acc[WM][WN];
    #pragma unroll
    for (int i = 0; i < WM; ++i)
        #pragma unroll
        for (int j = 0; j < WN; ++j) acc[i][j] = (f32x4){0.f, 0.f, 0.f, 0.f};

    const f16* pAh[AV]; const f16* pAl[AV]; int abase[AV]; bool avld[AV];
    #pragma unroll
    for (int i = 0; i < AV; ++i) {
        int seg = tid * AV + i;
        int row = seg >> 2, ko = (seg & 3) * 8;
        int gr = bm + row;
        avld[i] = gr < M;
        pAh[i] = Ah + (size_t)(avld[i] ? gr : 0) * lda + ko;
        if (P3) pAl[i] = Al + (size_t)(avld[i] ? gr : 0) * lda + ko;
        abase[i] = row * LDH + ko;
    }
    const f16* pBh[BV]; const f16* pBl[BV]; int bbase[BV]; bool bvld[BV];
    #pragma unroll
    for (int i = 0; i < BV; ++i) {
        int seg = tid * BV + i;
        int row = seg >> 2, ko = (seg & 3) * 8;
        int gr = bn + row;
        bvld[i] = gr < N;
        pBh[i] = Bh + (size_t)(bvld[i] ? gr : 0) * ldb + ko;
        if (P3) pBl[i] = Bl + (size_t)(bvld[i] ? gr : 0) * ldb + ko;
        bbase[i] = row * LDH + ko;
    }

    const i32x4 zz = {0, 0, 0, 0};
    i32x4 rAh[AV], rAl[AV], rBh[BV], rBl[BV];

    auto load_step = [&](int k0) {
        #pragma unroll
        for (int i = 0; i < AV; ++i) {
            rAh[i] = avld[i] ? *(const i32x4*)(pAh[i] + k0) : zz;
            if (P3) rAl[i] = avld[i] ? *(const i32x4*)(pAl[i] + k0) : zz;
        }
        #pragma unroll
        for (int i = 0; i < BV; ++i) {
            rBh[i] = bvld[i] ? *(const i32x4*)(pBh[i] + k0) : zz;
            if (P3) rBl[i] = bvld[i] ? *(const i32x4*)(pBl[i] + k0) : zz;
        }
    };
    load_step(ksBeg);

    int kfo = (lane >> 4) * 8;
    int rr = lane & 15;

    for (int k0 = ksBeg; k0 < ksEnd; k0 += 32) {
        __syncthreads();
        #pragma unroll
        for (int i = 0; i < AV; ++i) {
            *(i32x4*)&sAh[abase[i]] = rAh[i];
            if (P3) *(i32x4*)&sAl[abase[i]] = rAl[i];
        }
        #pragma unroll
        for (int i = 0; i < BV; ++i) {
            *(i32x4*)&sBh[bbase[i]] = rBh[i];
            if (P3) *(i32x4*)&sBl[bbase[i]] = rBl[i];
        }
        __syncthreads();
        if (k0 + 32 < ksEnd) load_step(k0 + 32);

        f16x8 fah[WM], fal[WM], fbh[WN], fbl[WN];
        #pragma unroll
        for (int m = 0; m < WM; ++m) {
            int row = wr * (WM * 16) + m * 16 + rr;
            fah[m] = *(const f16x8*)&sAh[row * LDH + kfo];
            if (P3) fal[m] = *(const f16x8*)&sAl[row * LDH + kfo];
        }
        #pragma unroll
        for (int n = 0; n < WN; ++n) {
            int row = wc * (WN * 16) + n * 16 + rr;
            fbh[n] = *(const f16x8*)&sBh[row * LDH + kfo];
            if (P3) fbl[n] = *(const f16x8*)&sBl[row * LDH + kfo];
        }
        #pragma unroll
        for (int m = 0; m < WM; ++m)
            #pragma unroll
            for (int n = 0; n < WN; ++n) {
                acc[m][n] = __builtin_amdgcn_mfma_f32_16x16x32_f16(fah[m], fbh[n], acc[m][n], 0, 0, 0);
                if (P3) {
                    acc[m][n] = __builtin_amdgcn_mfma_f32_16x16x32_f16(fah[m], fbl[n], acc[m][n], 0, 0, 0);
                    acc[m][n] = __builtin_amdgcn_mfma_f32_16x16x32_f16(fal[m], fbh[n], acc[m][n], 0, 0, 0);
                }
            }
    }

    int crl = lane >> 4;
    size_t zoff = (SPLITK > 1) ? (size_t)blockIdx.z * M : 0;
    #pragma unroll
    for (int m = 0; m < WM; ++m) {
        #pragma unroll
        for (int n = 0; n < WN; ++n) {
            int gn = bn + wc * (WN * 16) + n * 16 + rr;
            if (gn >= N) continue;
            #pragma unroll
            for (int r = 0; r < 4; ++r) {
                int gm = bm + wr * (WM * 16) + m * 16 + crl * 4 + r;
                if (gm >= M) continue;
                if (SPLITK > 1) {
                    C[(zoff + gm) * ldc + gn] = acc[m][n][r];
                } else {
                    float v = acc[m][n][r] + bias[gn];
                    if (MODE == 1) {
                        float s = g[gn] / sqrtf(var[gn] + BN_EPS);
                        v = (v - mean[gn]) * s + be[gn];
                        v = fmaxf(v, 0.f);
                    } else if (MODE == 2) {
                        v = fmaxf(v, 0.f);
                    }
                    C[(size_t)gm * ldc + gn] = v;
                }
            }
        }
    }
}

// ====================== split-K reduce + epilogue (fp32 out) ======================
template<int MODE>
__global__ void reduce_ep(const float* __restrict__ part, float* __restrict__ C,
                          int M, int N, int ldc, int KS,
                          const float* __restrict__ bias, const float* __restrict__ g,
                          const float* __restrict__ be, const float* __restrict__ mean,
                          const float* __restrict__ var)
{
    int idx = blockIdx.x * blockDim.x + threadIdx.x;
    if (idx >= M * N) return;
    int m = idx / N, n = idx % N;
    float v = 0.f;
    for (int ks = 0; ks < KS; ++ks) v += part[((size_t)ks * M + m) * N + n];
    v += bias[n];
    if (MODE == 1) {
        float s = g[n] / sqrtf(var[n] + BN_EPS);
        v = (v - mean[n]) * s + be[n];
        v = fmaxf(v, 0.f);
    } else if (MODE == 2) {
        v = fmaxf(v, 0.f);
    }
    C[(size_t)m * ldc + n] = v;
}

// ====================== split-K reduce + BN/relu -> f16 (k-padded) ======================
__global__ void reduce_ep_f16(const float* __restrict__ part, f16* __restrict__ Ch,
                              int M, int N, int Npad, int KS,
                              const float* __restrict__ bias, const float* __restrict__ g,
                              const float* __restrict__ be, const float* __restrict__ mean,
                              const float* __restrict__ var)
{
    int idx = blockIdx.x * blockDim.x + threadIdx.x;
    if (idx >= M * Npad) return;
    int m = idx / Npad, n = idx % Npad;
    float v = 0.f;
    if (n < N) {
        for (int ks = 0; ks < KS; ++ks) v += part[((size_t)ks * M + m) * N + n];
        v += bias[n];
        float s = g[n] / sqrtf(var[n] + BN_EPS);
        v = (v - mean[n]) * s + be[n];
        v = fmaxf(v, 0.f);
    }
    Ch[(size_t)m * Npad + n] = (f16)v;
}

// ====================== NHWC maxpool ======================
__global__ void maxpool3s2_nhwc(const float* __restrict__ in, float* __restrict__ out,
                                int Bn, int C, int Hin, int Win, int Hout, int Wout)
{
    int idx = blockIdx.x * blockDim.x + threadIdx.x;
    int total = Bn * Hout * Wout * C;
    if (idx >= total) return;
    int c = idx % C, t = idx / C;
    int ow = t % Wout; t /= Wout;
    int oh = t % Hout; int b = t / Hout;
    const float* base = in + (((size_t)b * Hin + oh * 2) * Win + ow * 2) * C + c;
    float v = -INFINITY;
    #pragma unroll
    for (int kh = 0; kh < 3; ++kh)
        #pragma unroll
        for (int kw = 0; kw < 3; ++kw)
            v = fmaxf(v, base[((size_t)kh * Win + kw) * C]);
    out[idx] = v;
}

// ====================== ROI max-pool -> (own_h, own_l) f16 pair; row N zeroed ======================
__global__ void roi_pool_kernel(const float* __restrict__ feat, const float* __restrict__ bboxes,
                                f16* __restrict__ own_h, f16* __restrict__ own_l,
                                int N, int C, int H, int W)
{
    int idx = blockIdx.x * blockDim.x + threadIdx.x;
    if (idx >= (N + 1) * C) return;
    int n = idx / C, c = idx % C;
    f16* oh16 = own_h + (size_t)n * (C * 9) + (size_t)c * 9;
    f16* ol16 = own_l + (size_t)n * (C * 9) + (size_t)c * 9;
    if (n == N) {
        #pragma unroll
        for (int j = 0; j < 9; ++j) { oh16[j] = (f16)0.f; ol16[j] = (f16)0.f; }
        return;
    }
    const float* bb = bboxes + (size_t)n * 5;
    int img = (int)bb[0];
    const float SC = 13.0f / 224.0f;
    int x1 = (int)rintf(bb[1] * SC);
    int y1 = (int)rintf(bb[2] * SC);
    int x2 = (int)rintf(bb[3] * SC);
    int y2 = (int)rintf(bb[4] * SC);
    int roi_w = max(x2 - x1 + 1, 1);
    int roi_h = max(y2 - y1 + 1, 1);
    const float* f = feat + (size_t)img * H * W * C + c;
    for (int ph = 0; ph < 3; ++ph) {
        int hstart = min(max(y1 + (ph * roi_h) / 3, 0), H);
        int hend   = min(max(y1 + ((ph + 1) * roi_h + 2) / 3, 0), H);
        for (int pw = 0; pw < 3; ++pw) {
            int wstart = min(max(x1 + (pw * roi_w) / 3, 0), W);
            int wend   = min(max(x1 + ((pw + 1) * roi_w + 2) / 3, 0), W);
            float v;
            if (hend <= hstart || wend <= wstart) {
                v = 0.f;
            } else {
                v = -INFINITY;
                for (int hh = hstart; hh < hend; ++hh)
                    for (int ww = wstart; ww < wend; ++ww)
                        v = fmaxf(v, f[((size_t)hh * W + ww) * C]);
            }
            f16 h = (f16)v;
            oh16[ph * 3 + pw] = h;
            ol16[ph * 3 + pw] = (f16)(v - (float)h);
        }
    }
}

// ====================== attention projections ======================
__global__ __launch_bounds__(128) void proj_kernel(
    const float* __restrict__ enc_all, const float* __restrict__ att_w,
    float* __restrict__ s_own, float* __restrict__ proj_hi, int R, int H, int Nroi)
{
    int r = blockIdx.x, tid = threadIdx.x;
    const float* row = enc_all + (size_t)r * H;
    float plo = 0.f, phi = 0.f;
    for (int hh = tid; hh < H; hh += 128) {
        float v = row[hh];
        plo += v * att_w[hh];
        phi += v * att_w[H + hh];
    }
    __shared__ float slo[128], shi[128];
    slo[tid] = plo; shi[tid] = phi;
    __syncthreads();
    for (int s = 64; s > 0; s >>= 1) {
        if (tid < s) { slo[tid] += slo[tid + s]; shi[tid] += shi[tid + s]; }
        __syncthreads();
    }
    if (tid == 0) {
        if (r < Nroi) s_own[r] = slo[0];
        proj_hi[r] = shi[0];
    }
}

// ====================== attention softmax + combine -> comb_h/comb_l directly ======================
__global__ __launch_bounds__(512) void att_combine_kernel(
    const float* __restrict__ enc_all, const int* __restrict__ ci,
    const float* __restrict__ s_own, const float* __restrict__ proj_hi,
    const float* __restrict__ att_b,
    const f16* __restrict__ own_h, const f16* __restrict__ own_l,
    const float* __restrict__ bboxes,
    f16* __restrict__ comb_h, f16* __restrict__ comb_l,
    int N, int H)
{
    int n = blockIdx.x, tid = threadIdx.x;
    __shared__ float wts[K2];
    __shared__ int rows[K2];
    if (tid < K2) {
        int idx = ci[(size_t)n * K2 + tid];
        int row = (idx < 0) ? N : idx;
        rows[tid] = row;
        wts[tid] = s_own[n] + proj_hi[row] + att_b[0];
    }
    __syncthreads();
    if (tid == 0) {
        float mx = wts[0];
        #pragma unroll
        for (int k = 1; k < K2; ++k) mx = fmaxf(mx, wts[k]);
        float sum = 0.f;
        float e[K2];
        #pragma unroll
        for (int k = 0; k < K2; ++k) { e[k] = expf(wts[k] - mx); sum += e[k]; }
        float inv = 1.f / sum;
        #pragma unroll
        for (int k = 0; k < K2; ++k) wts[k] = e[k] * inv;
    }
    __syncthreads();

    f16* ch = comb_h + (size_t)n * KPAD_DEC;
    f16* cl = comb_l + (size_t)n * KPAD_DEC;

    if (tid < H) {
        float acc = 0.f;
        #pragma unroll
        for (int k = 0; k < K2; ++k)
            acc += wts[k] * enc_all[(size_t)rows[k] * H + tid];
        f16 h = (f16)acc;
        ch[N_VIS + tid] = h;
        cl[N_VIS + tid] = (f16)(acc - (float)h);
    }
    {
        const f16x8* oh8 = (const f16x8*)(own_h + (size_t)n * N_VIS);
        const f16x8* ol8 = (const f16x8*)(own_l + (size_t)n * N_VIS);
        f16x8* ch8 = (f16x8*)ch;
        f16x8* cl8 = (f16x8*)cl;
        for (int j = tid; j < N_VIS / 8; j += 512) {
            ch8[j] = oh8[j];
            cl8[j] = ol8[j];
        }
    }
    if (tid >= 488 && tid < 504) {
        int col = NTOT + (tid - 488);
        ch[col] = (f16)0.f;
        cl[col] = (f16)0.f;
    }
    if (tid >= 508) {
        int j = tid - 508;
        float x1 = bboxes[(size_t)n * 5 + 1];
        float y1 = bboxes[(size_t)n * 5 + 2];
        float x2 = bboxes[(size_t)n * 5 + 3];
        float y2 = bboxes[(size_t)n * 5 + 4];
        float vals[4] = { x1, y1, x2 - x1, y2 - y1 };
        float v = vals[j];
        f16 h = (f16)v;
        ch[N_VIS + HID + j] = h;
        cl[N_VIS + HID + j] = (f16)(v - (float)h);
    }
}

// ====================== out = h @ w2 + b2 (fallback) ======================
__global__ __launch_bounds__(256) void gemv4_kernel(
    const float* __restrict__ h, const float* __restrict__ w2,
    const float* __restrict__ b2, float* __restrict__ out, int K)
{
    int m = blockIdx.x, tid = threadIdx.x;
    const float* hr = h + (size_t)m * K;
    float a0 = 0.f, a1 = 0.f, a2 = 0.f, a3 = 0.f;
    for (int k = tid; k < K; k += 256) {
        float x = hr[k];
        const float* wr = w2 + (size_t)k * 4;
        a0 += x * wr[0]; a1 += x * wr[1]; a2 += x * wr[2]; a3 += x * wr[3];
    }
    __shared__ float red[256][4];
    red[tid][0] = a0; red[tid][1] = a1; red[tid][2] = a2; red[tid][3] = a3;
    __syncthreads();
    for (int s = 128; s > 0; s >>= 1) {
        if (tid < s) {
            #pragma unroll
            for (int j = 0; j < 4; ++j) red[tid][j] += red[tid + s][j];
        }
        __syncthreads();
    }
    if (tid < 4) out[(size_t)m * 4 + tid] = red[0][tid] + b2[tid];
}

// ====================== fused: (part0+part1) -> BN/relu -> @ w2 + b2 ======================
__global__ __launch_bounds__(256) void gemv4_fused_kernel(
    const float* __restrict__ part, const float* __restrict__ w2,
    const float* __restrict__ b2, const float* __restrict__ bias,
    const float* __restrict__ g, const float* __restrict__ be,
    const float* __restrict__ mean, const float* __restrict__ var,
    float* __restrict__ out, int M, int K)
{
    int m = blockIdx.x, tid = threadIdx.x;
    const float* p0 = part + (size_t)m * K;
    const float* p1 = part + ((size_t)M + m) * K;
    float a0 = 0.f, a1 = 0.f, a2 = 0.f, a3 = 0.f;
    for (int k = tid; k < K; k += 256) {
        float v = p0[k] + p1[k] + bias[k];
        float s = g[k] / sqrtf(var[k] + BN_EPS);
        v = (v - mean[k]) * s + be[k];
        v = fmaxf(v, 0.f);
        const float* wr = w2 + (size_t)k * 4;
        a0 += v * wr[0]; a1 += v * wr[1]; a2 += v * wr[2]; a3 += v * wr[3];
    }
    __shared__ float red[256][4];
    red[tid][0] = a0; red[tid][1] = a1; red[tid][2] = a2; red[tid][3] = a3;
    __syncthreads();
    for (int s = 128; s > 0; s >>= 1) {
        if (tid < s) {
            #pragma unroll
            for (int j = 0; j < 4; ++j) red[tid][j] += red[tid + s][j];
        }
        __syncthreads();
    }
    if (tid < 4) out[(size_t)m * 4 + tid] = red[0][tid] + b2[tid];
}

extern "C" void kernel_launch(void* const* d_in, const int* in_sizes, int n_in,
                              void* d_out, int out_size, void* d_ws, size_t ws_size,
                              hipStream_t stream)
{
    const float* images = (const float*)d_in[0];
    const float* bboxes = (const float*)d_in[1];
    const int*   ci     = (const int*)  d_in[2];
    const float* c1w = (const float*)d_in[3];
    const float* c1b = (const float*)d_in[4];
    const float* c2w = (const float*)d_in[5];
    const float* c2b = (const float*)d_in[6];
    const float* c3w = (const float*)d_in[7];
    const float* c3b = (const float*)d_in[8];
    const float* enc_w1 = (const float*)d_in[9];
    const float* enc_b1 = (const float*)d_in[10];
    const float* enc_g  = (const float*)d_in[11];
    const float* enc_be = (const float*)d_in[12];
    const float* enc_m  = (const float*)d_in[13];
    const float* enc_v  = (const float*)d_in[14];
    const float* enc_w2 = (const float*)d_in[15];
    const float* enc_b2 = (const float*)d_in[16];
    const float* att_w  = (const float*)d_in[17];
    const float* att_b  = (const float*)d_in[18];
    const float* dec_w1 = (const float*)d_in[19];
    const float* dec_b1 = (const float*)d_in[20];
    const float* dec_g  = (const float*)d_in[21];
    const float* dec_be = (const float*)d_in[22];
    const float* dec_m  = (const float*)d_in[23];
    const float* dec_v  = (const float*)d_in[24];
    const float* dec_w2 = (const float*)d_in[25];
    const float* dec_b2 = (const float*)d_in[26];
    float* out = (float*)d_out;

    float* ws = (float*)d_ws;
    size_t off = 0;
    auto alloc = [&](size_t n) { float* p = ws + off; off += (n + 255) & ~(size_t)255; return p; };

    float* own      = alloc((size_t)(NROI + 1) * N_VIS);       // region reused for comb_h/comb_l
    float* featN    = alloc((size_t)BATCH * 13 * 13 * C_FEAT);
    float* mid      = alloc((size_t)(NROI + 1) * HID);         // fallback path only
    float* enc_all  = alloc((size_t)(NROI + 1) * HID);
    float* s_own    = alloc(NROI);
    float* proj_hi  = alloc(NROI + 1);
    float* combined = alloc((size_t)NROI * NTOT);
    float* hbuf     = alloc((size_t)NROI * NTOT);
    size_t base_off = off;

    const size_t BTD_FL = 7128320;
    bool full_dec = (ws_size >= (base_off + 2 * BTD_FL) * sizeof(float));
    float* Btd_h_f = ws + base_off;
    float* Btd_l_f = ws + base_off + BTD_FL;

    float* S = combined;

    f16* wt1_h = (f16*)(S + 6651904);
    f16* wt2_h = wt1_h + 24576;
    f16* wt3_h = wt2_h + 307200;

    convert_rowmajor<<<(64 * 384 + 255) / 256, 256, 0, stream>>>(c1w, wt1_h, 64, 363, 384);
    convert_rowmajor<<<(192 * 1600 + 255) / 256, 256, 0, stream>>>(c2w, wt2_h, 192, 1600, 1600);
    convert_rowmajor<<<(384 * 1728 + 255) / 256, 256, 0, stream>>>(c3w, wt3_h, 384, 1728, 1728);

    float* conv1o = S;
    float* pool1  = S + 1548800;
    float* conv2o = S;

    if (full_dec) {
        f16* colF = (f16*)Btd_h_f;
        float* part2 = S + 1922048;
        float* pool2 = S + 4161536;
        float* part3 = S;

        {
            int total = 8 * 3025 * 384;
            im2col1_f16<<<(total + 255) / 256, 256, 0, stream>>>(images, colF, 0, 8);
            dim3 grid(1, (8 * 3025 + 63) / 64);
            gemm_f16x3<64, 64, 256, 2, 0, 1, 1><<<grid, 256, 0, stream>>>(
                colF, nullptr, 384, wt1_h, nullptr, 384,
                conv1o, 64, 8 * 3025, 64, 384,
                c1b, nullptr, nullptr, nullptr, nullptr);
        }
        maxpool3s2_nhwc<<<(BATCH * 27 * 27 * 64 + 255) / 256, 256, 0, stream>>>(
            conv1o, pool1, BATCH, 64, 55, 55, 27, 27);

        {
            int total = 8 * 729 * 1600;
            im2col2_f16<<<(total + 255) / 256, 256, 0, stream>>>(pool1, colF, 0, 8);
            dim3 grid(3, (8 * 729 + 63) / 64, 2);
            gemm_f16x3<64, 64, 256, 0, 0, 2, 1><<<grid, 256, 0, stream>>>(
                colF, nullptr, 1600, wt2_h, nullptr, 1600,
                part2, 192, 8 * 729, 192, 1600,
                nullptr, nullptr, nullptr, nullptr, nullptr);
            reduce_ep<2><<<(8 * 729 * 192 + 255) / 256, 256, 0, stream>>>(
                part2, conv2o, 8 * 729, 192, 192, 2, c2b, nullptr, nullptr, nullptr, nullptr);
        }
        maxpool3s2_nhwc<<<(BATCH * 13 * 13 * 192 + 255) / 256, 256, 0, stream>>>(
            conv2o, pool2, BATCH, 192, 27, 27, 13, 13);

        {
            int total = 8 * 169 * 1728;
            im2col3_f16<<<(total + 255) / 256, 256, 0, stream>>>(pool2, colF);
            dim3 grid(6, (8 * 169 + 63) / 64, 2);
            gemm_f16x3<64, 64, 256, 0, 0, 2, 1><<<grid, 256, 0, stream>>>(
                colF, nullptr, 1728, wt3_h, nullptr, 1728,
                part3, 384, 8 * 169, 384, 1728,
                nullptr, nullptr, nullptr, nullptr, nullptr);
            reduce_ep<0><<<(8 * 169 * 384 + 255) / 256, 256, 0, stream>>>(
                part3, featN, 8 * 169, 384, 384, 2, c3b, nullptr, nullptr, nullptr, nullptr);
        }
    } else {
        f16* col_h = (f16*)(S + 1922048);
        float* pool2 = S + 1548800;
        for (int ch = 0; ch < 2; ++ch) {
            int b0 = ch * 4, nb = 4;
            int total = nb * 3025 * 384;
            im2col1_f16<<<(total + 255) / 256, 256, 0, stream>>>(images, col_h, b0, nb);
            dim3 grid(1, (nb * 3025 + 63) / 64);
            gemm_f16x3<64, 64, 256, 2, 0, 1, 1><<<grid, 256, 0, stream>>>(
                col_h, nullptr, 384, wt1_h, nullptr, 384,
                conv1o + (size_t)b0 * 3025 * 64, 64, nb * 3025, 64, 384,
                c1b, nullptr, nullptr, nullptr, nullptr);
        }
        maxpool3s2_nhwc<<<(BATCH * 27 * 27 * 64 + 255) / 256, 256, 0, stream>>>(
            conv1o, pool1, BATCH, 64, 55, 55, 27, 27);
        for (int ch = 0; ch < 2; ++ch) {
            int b0 = ch * 4, nb = 4;
            int total = nb * 729 * 1600;
            im2col2_f16<<<(total + 255) / 256, 256, 0, stream>>>(pool1, col_h, b0, nb);
            dim3 grid(3, (nb * 729 + 63) / 64);
            gemm_f16x3<64, 64, 256, 2, 0, 1, 1><<<grid, 256, 0, stream>>>(
                col_h, nullptr, 1600, wt2_h, nullptr, 1600,
                conv2o + (size_t)b0 * 729 * 192, 192, nb * 729, 192, 1600,
                c2b, nullptr, nullptr, nullptr, nullptr);
        }
        maxpool3s2_nhwc<<<(BATCH * 13 * 13 * 192 + 255) / 256, 256, 0, stream>>>(
            conv2o, pool2, BATCH, 192, 27, 27, 13, 13);
        {
            int total = 8 * 169 * 1728;
            im2col3_f16<<<(total + 255) / 256, 256, 0, stream>>>(pool2, col_h);
            dim3 grid(6, (8 * 169 + 63) / 64);
            gemm_f16x3<64, 64, 256, 0, 0, 1, 1><<<grid, 256, 0, stream>>>(
                col_h, nullptr, 1728, wt3_h, nullptr, 1728,
                featN, 384, 8 * 169, 384, 1728,
                c3b, nullptr, nullptr, nullptr, nullptr);
        }
    }

    // ---- ROI pool -> own_h + own_l (f16), zero row fused ----
    f16* own_h = (f16*)(S + 0);
    f16* own_l = (f16*)(S + 1771200);
    roi_pool_kernel<<<((NROI + 1) * C_FEAT + 255) / 256, 256, 0, stream>>>(
        featN, bboxes, own_h, own_l, NROI, C_FEAT, 13, 13);

    // ---- encoder layer 1 (1-pass fp16) ----
    f16* encB_h = (f16*)(S + 3542400);
    {
        dim3 tg((N_VIS + 31) / 32, (HID + 31) / 32);
        transpose_convert<<<tg, 256, 0, stream>>>(enc_w1, N_VIS, HID, 0, HID, N_VIS, encB_h);
    }
    f16* mid_h = (f16*)(S + 5290800);
    f16* e2B_h = (f16*)(S + 5454800);
    if (full_dec) {
        float* part1 = S + 4060800;
        dim3 grid((HID + 63) / 64, (NROI + 1 + 63) / 64, 4);
        gemm_f16x3<64, 64, 256, 0, 0, 4, 1><<<grid, 256, 0, stream>>>(
            own_h, nullptr, N_VIS, encB_h, nullptr, N_VIS,
            part1, HID, NROI + 1, HID, N_VIS,
            nullptr, nullptr, nullptr, nullptr, nullptr);
        reduce_ep_f16<<<((NROI + 1) * KPAD_ENC2 + 255) / 256, 256, 0, stream>>>(
            part1, mid_h, NROI + 1, HID, KPAD_ENC2, 4, enc_b1, enc_g, enc_be, enc_m, enc_v);
    } else {
        dim3 grid((HID + 63) / 64, (NROI + 1 + 63) / 64);
        gemm_f16x3<64, 64, 256, 1, 0, 1, 1><<<grid, 256, 0, stream>>>(
            own_h, nullptr, N_VIS, encB_h, nullptr, N_VIS,
            mid, HID, NROI + 1, HID, N_VIS,
            enc_b1, enc_g, enc_be, enc_m, enc_v);
        convert_rowmajor<<<((NROI + 1) * KPAD_ENC2 + 255) / 256, 256, 0, stream>>>(
            mid, mid_h, NROI + 1, HID, KPAD_ENC2);
    }

    // ---- encoder layer 2 (1-pass fp16) ----
    {
        dim3 tg((HID + 31) / 32, (HID + 31) / 32);
        transpose_convert<<<tg, 256, 0, stream>>>(enc_w2, HID, HID, 0, HID, KPAD_ENC2, e2B_h);
    }
    {
        dim3 grid((HID + 63) / 64, (NROI + 1 + 63) / 64);
        gemm_f16x3<64, 64, 256, 0, 0, 1, 1><<<grid, 256, 0, stream>>>(
            mid_h, nullptr, KPAD_ENC2, e2B_h, nullptr, KPAD_ENC2,
            enc_all, HID, NROI + 1, HID, KPAD_ENC2,
            enc_b2, nullptr, nullptr, nullptr, nullptr);
    }

    // ---- attention -> comb_h/comb_l directly ----
    f16* comb_h = (f16*)own;
    f16* comb_l = (f16*)(own + 1933312);
    proj_kernel<<<NROI + 1, 128, 0, stream>>>(enc_all, att_w, s_own, proj_hi, NROI + 1, HID, NROI);
    att_combine_kernel<<<NROI, 512, 0, stream>>>(enc_all, ci, s_own, proj_hi, att_b,
                                                 own_h, own_l, bboxes, comb_h, comb_l,
                                                 NROI, HID);

    // ---- decoder layer 1 (3-pass f16x3, proven 128x128/512-thread/splitK2 config) ----
    if (full_dec) {
        f16* Btd_h = (f16*)Btd_h_f;
        f16* Btd_l = (f16*)Btd_l_f;
        dim3 tg(KPAD_DEC / 32, KPAD_DEC / 32);
        transpose_split<<<tg, 256, 0, stream>>>(dec_w1, NTOT, NTOT, 0, KPAD_DEC, KPAD_DEC, Btd_h, Btd_l);
        float* part = combined;                // spans combined+hbuf (2 slices)
        dim3 grid(240, 1, 2);
        gemm_f16x3<128, 128, 512, 1, 2, 2, 3><<<grid, 512, 0, stream>>>(
            comb_h, comb_l, KPAD_DEC, Btd_h, Btd_l, KPAD_DEC,
            part, NTOT, NROI, NTOT, KPAD_DEC,
            nullptr, nullptr, nullptr, nullptr, nullptr);
        gemv4_fused_kernel<<<NROI, 256, 0, stream>>>(
            part, dec_w2, dec_b2, dec_b1, dec_g, dec_be, dec_m, dec_v,
            out, NROI, NTOT);
    } else {
        f16* Btc_h = (f16*)(S + 0);
        f16* Btc_l = (f16*)(S + 1774720);
        for (int c = 0; c < 4; ++c) {
            int nc0 = c * 940, NC = 940;
            dim3 tg(KPAD_DEC / 32, (NC + 31) / 32);
            transpose_split<<<tg, 256, 0, stream>>>(dec_w1, NTOT, NTOT, nc0, NC, KPAD_DEC, Btc_h, Btc_l);
            dim3 grid((NC + 63) / 64, NROI / 64);
            gemm_f16x3<64, 64, 256, 1, 0, 1, 3><<<grid, 256, 0, stream>>>(
                comb_h, comb_l, KPAD_DEC, Btc_h, Btc_l, KPAD_DEC,
                hbuf + nc0, NTOT, NROI, NC, KPAD_DEC,
                dec_b1 + nc0, dec_g + nc0, dec_be + nc0, dec_m + nc0, dec_v + nc0);
        }
        gemv4_kernel<<<NROI, 256, 0, stream>>>(hbuf, dec_w2, dec_b2, out, NTOT);
    }
}